// Round 1
// baseline (178.152 us; speedup 1.0000x reference)
//
#include <hip/hip_runtime.h>
#include <math.h>

#define NB 512
#define NATOMS 1024
#define NG 256
#define NL 8
#define NK 128
#define ND 6

#define KBT 0.59616123f     // 0.0019872041 * 300
#define ALPHA_C 10.0f
#define BW_C 0.15f

__device__ __forceinline__ float wred_max(float v) {
#pragma unroll
  for (int m = 32; m >= 1; m >>= 1) v = fmaxf(v, __shfl_xor(v, m, 64));
  return v;
}
__device__ __forceinline__ float wred_min(float v) {
#pragma unroll
  for (int m = 32; m >= 1; m >>= 1) v = fminf(v, __shfl_xor(v, m, 64));
  return v;
}
__device__ __forceinline__ float wred_sum(float v) {
#pragma unroll
  for (int m = 32; m >= 1; m >>= 1) v += __shfl_xor(v, m, 64);
  return v;
}

// One wave per (b,g) pair.  p = g*NB + b so the 4 waves of a block share g
// (kde tile stays hot in L1).  Lane owns k = lane and k+64.
__global__ __launch_bounds__(256) void kde_gmin_kernel(
    const float* __restrict__ positions, const float* __restrict__ kde,
    const float* __restrict__ weight, const float* __restrict__ offs,
    const int* __restrict__ atom_idxs, const int* __restrict__ gsizes,
    float* __restrict__ gmin_out) {
  const int lane = threadIdx.x & 63;
  const int wid  = threadIdx.x >> 6;
  const int p = blockIdx.x * 4 + wid;
  const int b = p & (NB - 1);
  const int g = p >> 9;           // p / NB

  const float inv2bw2 = 1.0f / (2.0f * BW_C * BW_C);
  const float log_norm = logf((float)NK)
                       + 0.5f * (float)ND * logf(2.0f * (float)M_PI * BW_C * BW_C);

  int gs = gsizes[g];
  int nl = gs < 1 ? 1 : (gs > NL ? NL : gs);   // sizes = clamp(max(gs,1), L)

  const float* pb = positions + (size_t)b * NATOMS * 3;

  float gmin = INFINITY;

  for (int l = 0; l < nl; ++l) {
    // gather 4 atom positions (wave-uniform addresses)
    const int4 idx = *reinterpret_cast<const int4*>(atom_idxs + ((g * NL + l) << 2));
    const int ids[4] = {idx.x, idx.y, idx.z, idx.w};
    float ax[4], ay[4], az[4];
#pragma unroll
    for (int j = 0; j < 4; ++j) {
      const float* pp = pb + ids[j] * 3;
      ax[j] = pp[0]; ay[j] = pp[1]; az[j] = pp[2];
    }
    // 6 pairwise distances, match ref rounding (sqrt then re-square)
    const int PI_[6] = {0, 0, 0, 1, 1, 2};
    const int PJ_[6] = {1, 2, 3, 2, 3, 3};
    float d[6]; float x2 = 0.0f;
#pragma unroll
    for (int q = 0; q < 6; ++q) {
      float dx = ax[PI_[q]] - ax[PJ_[q]];
      float dy = ay[PI_[q]] - ay[PJ_[q]];
      float dz = az[PI_[q]] - az[PJ_[q]];
      float dd = dx * dx + dy * dy + dz * dz + 1e-12f;
      d[q] = sqrtf(dd);
      x2 += d[q] * d[q];
    }
    // K=128 kernel evals: lane handles k=lane and k=lane+64
    const float* kb = kde + (size_t)((g * NL + l) * NK) * ND;
    float v0 = 0.0f, v1 = 0.0f;
#pragma unroll
    for (int t = 0; t < 2; ++t) {
      const int k = lane + (t << 6);
      const float2* mp = reinterpret_cast<const float2*>(kb + k * ND);  // 8B aligned (6 floats/k)
      float2 m01 = mp[0], m23 = mp[1], m45 = mp[2];
      float mu2 = m01.x * m01.x + m01.y * m01.y + m23.x * m23.x
                + m23.y * m23.y + m45.x * m45.x + m45.y * m45.y;
      float xmu = d[0] * m01.x + d[1] * m01.y + d[2] * m23.x
                + d[3] * m23.y + d[4] * m45.x + d[5] * m45.y;
      float sq = x2 + mu2 - 2.0f * xmu;
      float v = -sq * inv2bw2;
      if (t == 0) v0 = v; else v1 = v;
    }
    // logsumexp over K within the wave
    float m = wred_max(fmaxf(v0, v1));
    float s = expf(v0 - m) + expf(v1 - m);   // max term is exp(0)=1 -> S >= 1, always finite
    float S = wred_sum(s);
    float logP = m + logf(S) - log_norm;
    float energy = -KBT * logP;
    float scaled = energy * weight[g * NL + l] + offs[g * NL + l];
    gmin = fminf(gmin, scaled);
  }
  if (lane == 0) gmin_out[b * NG + g] = gmin;   // layout for coalesced stage-2 read
}

// One block per b: min over g, then logsumexp(-ALPHA*gmin) over g.
__global__ __launch_bounds__(256) void group_lse_kernel(
    const float* __restrict__ gmin_in, float* __restrict__ out) {
  const int b = blockIdx.x;
  const int lane = threadIdx.x & 63;
  const int wid  = threadIdx.x >> 6;
  float v = gmin_in[b * NG + threadIdx.x];
  __shared__ float sm[4], ss[4];
  float m = wred_min(v);
  if (lane == 0) sm[wid] = m;
  __syncthreads();
  float M = fminf(fminf(sm[0], sm[1]), fminf(sm[2], sm[3]));
  float e = expf(-ALPHA_C * (v - M));
  float s = wred_sum(e);
  if (lane == 0) ss[wid] = s;
  __syncthreads();
  if (threadIdx.x == 0) {
    float S = ss[0] + ss[1] + ss[2] + ss[3];
    out[b] = M - logf(S) / ALPHA_C;
  }
}

extern "C" void kernel_launch(void* const* d_in, const int* in_sizes, int n_in,
                              void* d_out, int out_size, void* d_ws, size_t ws_size,
                              hipStream_t stream) {
  const float* positions = (const float*)d_in[0];
  const float* kde       = (const float*)d_in[1];
  const float* weight    = (const float*)d_in[2];
  const float* offs      = (const float*)d_in[3];
  const int*   atom_idxs = (const int*)d_in[4];
  const int*   gsizes    = (const int*)d_in[5];
  float* out  = (float*)d_out;
  float* gmin = (float*)d_ws;   // NB*NG*4 = 512 KiB scratch

  dim3 blk(256);
  kde_gmin_kernel<<<dim3((NB * NG) / 4), blk, 0, stream>>>(
      positions, kde, weight, offs, atom_idxs, gsizes, gmin);
  group_lse_kernel<<<dim3(NB), blk, 0, stream>>>(gmin, out);
}

// Round 2
// 71.440 us; speedup vs baseline: 2.4937x; 2.4937x over previous
//
#include <hip/hip_runtime.h>
#include <math.h>

#define NB 512
#define NATOMS 1024
#define NG 256
#define NL 8
#define NK 128

#define KBT 0.59616123f          // 0.0019872041 * 300
#define ALPHA_C 10.0f
#define BW_C 0.15f
#define INV2BW2 22.222221f       // 1/(2*BW^2) = 1/0.045
#define INVBW2 44.444443f        // 1/BW^2
#define LOG_NORM (-1.0170649f)   // log(128) + 3*log(2*pi*BW^2)

// monotone float<->uint key (unsigned order == float order), for atomicMin
__device__ __forceinline__ unsigned fkey(float f) {
  unsigned u = __float_as_uint(f);
  return (u & 0x80000000u) ? ~u : (u | 0x80000000u);
}
__device__ __forceinline__ float funkey(unsigned k) {
  unsigned u = (k & 0x80000000u) ? (k ^ 0x80000000u) : ~k;
  return __uint_as_float(u);
}

__device__ __forceinline__ float wred_min(float v) {
#pragma unroll
  for (int m = 32; m >= 1; m >>= 1) v = fminf(v, __shfl_xor(v, m, 64));
  return v;
}
__device__ __forceinline__ float wred_sum(float v) {
#pragma unroll
  for (int m = 32; m >= 1; m >>= 1) v += __shfl_xor(v, m, 64);
  return v;
}

// Block = one (g, l, b-half).  Thread t owns batch b = bq*256 + t and does the
// full K=128 logsumexp serially in registers (4 independent online-LSE chains).
// kde-derived terms are wave-uniform -> precomputed once into LDS.
__global__ __launch_bounds__(256) void stage1_kernel(
    const float* __restrict__ positions, const float* __restrict__ kde,
    const float* __restrict__ weight, const float* __restrict__ offs,
    const int* __restrict__ atom_idxs, const int* __restrict__ gsizes,
    unsigned* __restrict__ gmin_u) {
  const int blk = blockIdx.x;          // ((g*NL)+l)*2 + bq
  const int g = blk >> 4;
  const int l = (blk >> 1) & 7;
  const int bq = blk & 1;

  int gs = gsizes[g];
  int nl = gs < 1 ? 1 : (gs > NL ? NL : gs);
  if (l >= nl) return;                 // block-uniform exit, before any sync

  __shared__ __align__(16) float tab[NK][8];   // [mu0'..mu5', h, pad]

  const int t = threadIdx.x;
  const float* kb = kde + (size_t)((g * NL + l) * NK) * 6;
  if (t < NK) {
    const float* mp = kb + t * 6;
    float m0 = mp[0], m1 = mp[1], m2 = mp[2], m3 = mp[3], m4 = mp[4], m5 = mp[5];
    float mu2 = m0 * m0 + m1 * m1 + m2 * m2 + m3 * m3 + m4 * m4 + m5 * m5;
    float4 lo = make_float4(m0 * INVBW2, m1 * INVBW2, m2 * INVBW2, m3 * INVBW2);
    float4 hi = make_float4(m4 * INVBW2, m5 * INVBW2, -mu2 * INV2BW2, 0.0f);
    *reinterpret_cast<float4*>(&tab[t][0]) = lo;
    *reinterpret_cast<float4*>(&tab[t][4]) = hi;
  }
  __syncthreads();

  const int b = bq * 256 + t;

  // gather 4 atom positions for this b
  const int4 idx = *reinterpret_cast<const int4*>(atom_idxs + ((g * NL + l) << 2));
  const int ids[4] = {idx.x, idx.y, idx.z, idx.w};
  const float* pb = positions + (size_t)b * NATOMS * 3;
  float ax[4], ay[4], az[4];
#pragma unroll
  for (int j = 0; j < 4; ++j) {
    const float* pp = pb + ids[j] * 3;
    ax[j] = pp[0]; ay[j] = pp[1]; az[j] = pp[2];
  }
  const int PI_[6] = {0, 0, 0, 1, 1, 2};
  const int PJ_[6] = {1, 2, 3, 2, 3, 3};
  float d[6]; float x2 = 0.0f;
#pragma unroll
  for (int q = 0; q < 6; ++q) {
    float dx = ax[PI_[q]] - ax[PJ_[q]];
    float dy = ay[PI_[q]] - ay[PJ_[q]];
    float dz = az[PI_[q]] - az[PJ_[q]];
    float dd = dx * dx + dy * dy + dz * dz + 1e-12f;
    d[q] = sqrtf(dd);
    x2 += d[q] * d[q];
  }
  const float c = -x2 * INV2BW2;   // constant over k: pulled out of the LSE

  // online logsumexp over K with 4 independent chains
  float m_[4] = {-1e30f, -1e30f, -1e30f, -1e30f};
  float s_[4] = {0.0f, 0.0f, 0.0f, 0.0f};
  for (int k = 0; k < NK; k += 4) {
#pragma unroll
    for (int j = 0; j < 4; ++j) {
      const float4* r = reinterpret_cast<const float4*>(&tab[k + j][0]);
      float4 A = r[0], Bv = r[1];
      float v = Bv.z;                       // h_k
      v = fmaf(A.x, d[0], v);
      v = fmaf(A.y, d[1], v);
      v = fmaf(A.z, d[2], v);
      v = fmaf(A.w, d[3], v);
      v = fmaf(Bv.x, d[4], v);
      v = fmaf(Bv.y, d[5], v);
      float nm = fmaxf(m_[j], v);
      s_[j] = fmaf(s_[j], __expf(m_[j] - nm), __expf(v - nm));
      m_[j] = nm;
    }
  }
  float M = fmaxf(fmaxf(m_[0], m_[1]), fmaxf(m_[2], m_[3]));
  float S = s_[0] * __expf(m_[0] - M) + s_[1] * __expf(m_[1] - M)
          + s_[2] * __expf(m_[2] - M) + s_[3] * __expf(m_[3] - M);

  float logP = c + M + __logf(S) + (-LOG_NORM) * 0.0f + LOG_NORM * 0.0f;
  logP = c + M + __logf(S) - LOG_NORM;
  float energy = -KBT * logP;
  float scaled = energy * weight[g * NL + l] + offs[g * NL + l];

  atomicMin(&gmin_u[g * NB + b], fkey(scaled));   // [g][b]: wave-contiguous
}

// One block per b: min over g, then logsumexp(-ALPHA*gmin) over g.
__global__ __launch_bounds__(256) void stage2_kernel(
    const unsigned* __restrict__ gmin_u, float* __restrict__ out) {
  const int b = blockIdx.x;
  const int t = threadIdx.x;
  const int lane = t & 63;
  const int wid = t >> 6;
  float v = funkey(gmin_u[t * NB + b]);
  __shared__ float sm[4], ss[4];
  float m = wred_min(v);
  if (lane == 0) sm[wid] = m;
  __syncthreads();
  float M = fminf(fminf(sm[0], sm[1]), fminf(sm[2], sm[3]));
  float e = __expf(-ALPHA_C * (v - M));
  float s = wred_sum(e);
  if (lane == 0) ss[wid] = s;
  __syncthreads();
  if (t == 0) {
    float S = ss[0] + ss[1] + ss[2] + ss[3];
    out[b] = M - __logf(S) / ALPHA_C;
  }
}

extern "C" void kernel_launch(void* const* d_in, const int* in_sizes, int n_in,
                              void* d_out, int out_size, void* d_ws, size_t ws_size,
                              hipStream_t stream) {
  const float* positions = (const float*)d_in[0];
  const float* kde       = (const float*)d_in[1];
  const float* weight    = (const float*)d_in[2];
  const float* offs      = (const float*)d_in[3];
  const int*   atom_idxs = (const int*)d_in[4];
  const int*   gsizes    = (const int*)d_in[5];
  float* out = (float*)d_out;
  unsigned* gmin_u = (unsigned*)d_ws;   // NG*NB*4 = 512 KiB (same as round 1)

  hipMemsetAsync(gmin_u, 0xFF, (size_t)NG * NB * sizeof(unsigned), stream);

  stage1_kernel<<<dim3(NG * NL * 2), dim3(256), 0, stream>>>(
      positions, kde, weight, offs, atom_idxs, gsizes, gmin_u);
  stage2_kernel<<<dim3(NB), dim3(256), 0, stream>>>(gmin_u, out);
}

// Round 4
// 44.835 us; speedup vs baseline: 3.9735x; 1.5934x over previous
//
#include <hip/hip_runtime.h>

#define NB 512
#define NATOMS 1024
#define NG 256
#define NL 8
#define NK 128

#define KBT 0.59616123f            // 0.0019872041 * 300
#define ALPHA_C 10.0f
#define LN2 0.6931471805599453f
#define LOG2E 1.4426950408889634f
#define INV2BW2 22.222221f         // 1/(2*0.15^2)
#define SCALE2 (INV2BW2 * LOG2E)   // log2-domain scale
#define LOG_NORM (-1.0170649f)     // log(128) + 3*log(2*pi*BW^2)

#define WL_CAP 2048                // max active (g,l) pairs = NG*NL

__device__ __forceinline__ float fexp2(float x) { return __builtin_amdgcn_exp2f(x); }
__device__ __forceinline__ float flog2(float x) { return __builtin_amdgcn_logf(x); }

// monotone float<->uint key (unsigned order == float order), for atomicMin
__device__ __forceinline__ unsigned fkey(float f) {
  unsigned u = __float_as_uint(f);
  return (u & 0x80000000u) ? ~u : (u | 0x80000000u);
}
__device__ __forceinline__ float funkey(unsigned k) {
  unsigned u = (k & 0x80000000u) ? (k ^ 0x80000000u) : ~k;
  return __uint_as_float(u);
}

__device__ __forceinline__ float wred_min(float v) {
#pragma unroll
  for (int m = 32; m >= 1; m >>= 1) v = fminf(v, __shfl_xor(v, m, 64));
  return v;
}
__device__ __forceinline__ float wred_sum(float v) {
#pragma unroll
  for (int m = 32; m >= 1; m >>= 1) v += __shfl_xor(v, m, 64);
  return v;
}

// One block, 256 threads (one per g): prefix-sum nl -> packed worklist of
// active (g,l) pairs.  wl[WL_CAP] holds the total count.
__global__ __launch_bounds__(256) void build_worklist(
    const int* __restrict__ gsizes, int* __restrict__ wl) {
  const int t = threadIdx.x;
  const int lane = t & 63, wid = t >> 6;
  int gs = gsizes[t];
  int nl = gs < 1 ? 1 : (gs > NL ? NL : gs);
  int x = nl;                       // inclusive scan within wave
#pragma unroll
  for (int m = 1; m < 64; m <<= 1) {
    int y = __shfl_up(x, m, 64);
    if (lane >= m) x += y;
  }
  __shared__ int wsum[4];
  if (lane == 63) wsum[wid] = x;
  __syncthreads();
  int off = 0;
  for (int i = 0; i < wid; ++i) off += wsum[i];
  int inc = off + x, exc = inc - nl;
  for (int j = 0; j < nl; ++j) wl[exc + j] = (t << 3) | j;
  if (t == 255) wl[WL_CAP] = inc;   // total active pairs
}

// Block = one (worklist entry, b-half).  Thread t owns b = bq*256 + t and does
// the K=128 logsumexp serially: 4 online chains, each merging groups of 4 k's
// (1.25 exps/k, short dependence chains).  All in log2 domain.
__global__ __launch_bounds__(256) void stage1_kernel(
    const float* __restrict__ positions, const float* __restrict__ kde,
    const float* __restrict__ weight, const float* __restrict__ offs,
    const int* __restrict__ atom_idxs, const int* __restrict__ wl,
    unsigned* __restrict__ gmin_u) {
  const int w = blockIdx.x >> 1;
  const int bq = blockIdx.x & 1;
  const int count = wl[WL_CAP];
  if (w >= count) return;                 // contiguous inactive tail
  const int e = wl[w];
  const int g = e >> 3, l = e & 7;
  const int gl = g * NL + l;

  __shared__ __align__(16) float tab[NK][8];   // [mu'0..5, h, pad] (log2 dom.)

  const int t = threadIdx.x;
  const float* kb = kde + (size_t)gl * NK * 6;
  if (t < NK) {
    const float* mp = kb + t * 6;
    float m0 = mp[0], m1 = mp[1], m2 = mp[2], m3 = mp[3], m4 = mp[4], m5 = mp[5];
    float mu2 = m0 * m0 + m1 * m1 + m2 * m2 + m3 * m3 + m4 * m4 + m5 * m5;
    const float cf = 2.0f * SCALE2;
    float4 lo = make_float4(m0 * cf, m1 * cf, m2 * cf, m3 * cf);
    float4 hi = make_float4(m4 * cf, m5 * cf, -mu2 * SCALE2, 0.0f);
    *reinterpret_cast<float4*>(&tab[t][0]) = lo;
    *reinterpret_cast<float4*>(&tab[t][4]) = hi;
  }
  __syncthreads();

  const int b = bq * 256 + t;
  const int4 idx = *reinterpret_cast<const int4*>(atom_idxs + (gl << 2));
  const int ids[4] = {idx.x, idx.y, idx.z, idx.w};
  const float* pb = positions + (size_t)b * NATOMS * 3;
  float ax[4], ay[4], az[4];
#pragma unroll
  for (int j = 0; j < 4; ++j) {
    const float* pp = pb + ids[j] * 3;
    ax[j] = pp[0]; ay[j] = pp[1]; az[j] = pp[2];
  }
  const int PI_[6] = {0, 0, 0, 1, 1, 2};
  const int PJ_[6] = {1, 2, 3, 2, 3, 3};
  float d[6]; float x2 = 0.0f;
#pragma unroll
  for (int q = 0; q < 6; ++q) {
    float dx = ax[PI_[q]] - ax[PJ_[q]];
    float dy = ay[PI_[q]] - ay[PJ_[q]];
    float dz = az[PI_[q]] - az[PJ_[q]];
    float dd = dx * dx + dy * dy + dz * dz + 1e-12f;
    d[q] = sqrtf(dd);
    x2 += d[q] * d[q];
  }
  const float c2 = -x2 * SCALE2;     // constant over k (log2 domain)

  // 4 independent online-LSE chains; each step merges a group of 4 k's.
  float m_[4] = {-1e30f, -1e30f, -1e30f, -1e30f};
  float s_[4] = {0.0f, 0.0f, 0.0f, 0.0f};
  for (int k0 = 0; k0 < NK; k0 += 16) {
#pragma unroll
    for (int j = 0; j < 4; ++j) {
      const int kk = k0 + (j << 2);
      float v[4];
#pragma unroll
      for (int i = 0; i < 4; ++i) {
        const float4* r = reinterpret_cast<const float4*>(&tab[kk + i][0]);
        float4 A = r[0], Bv = r[1];
        float vv = Bv.z;
        vv = fmaf(A.x, d[0], vv);
        vv = fmaf(A.y, d[1], vv);
        vv = fmaf(A.z, d[2], vv);
        vv = fmaf(A.w, d[3], vv);
        vv = fmaf(Bv.x, d[4], vv);
        vv = fmaf(Bv.y, d[5], vv);
        v[i] = vv;
      }
      float gm = fmaxf(fmaxf(v[0], v[1]), fmaxf(v[2], v[3]));
      float p = fexp2(v[0] - gm) + fexp2(v[1] - gm)
              + fexp2(v[2] - gm) + fexp2(v[3] - gm);
      float nm = fmaxf(m_[j], gm);
      s_[j] = fmaf(s_[j], fexp2(m_[j] - nm), p * fexp2(gm - nm));
      m_[j] = nm;
    }
  }
  float M = fmaxf(fmaxf(m_[0], m_[1]), fmaxf(m_[2], m_[3]));
  float S = s_[0] * fexp2(m_[0] - M) + s_[1] * fexp2(m_[1] - M)
          + s_[2] * fexp2(m_[2] - M) + s_[3] * fexp2(m_[3] - M);

  float lse2 = c2 + M + flog2(S);            // log2(sum_k exp(v_k))
  float logP = lse2 * LN2 - LOG_NORM;
  float scaled = -KBT * logP * weight[gl] + offs[gl];
  atomicMin(&gmin_u[g * NB + b], fkey(scaled));
}

// One block per b: min over g, then logsumexp(-ALPHA*gmin) over g.
__global__ __launch_bounds__(256) void stage2_kernel(
    const unsigned* __restrict__ gmin_u, float* __restrict__ out) {
  const int b = blockIdx.x;
  const int t = threadIdx.x;
  const int lane = t & 63;
  const int wid = t >> 6;
  float v = funkey(gmin_u[t * NB + b]);
  __shared__ float sm[4], ss[4];
  float m = wred_min(v);
  if (lane == 0) sm[wid] = m;
  __syncthreads();
  float M = fminf(fminf(sm[0], sm[1]), fminf(sm[2], sm[3]));
  float e = fexp2(-ALPHA_C * LOG2E * (v - M));
  float s = wred_sum(e);
  if (lane == 0) ss[wid] = s;
  __syncthreads();
  if (t == 0) {
    float S = ss[0] + ss[1] + ss[2] + ss[3];
    out[b] = M - flog2(S) * LN2 / ALPHA_C;
  }
}

extern "C" void kernel_launch(void* const* d_in, const int* in_sizes, int n_in,
                              void* d_out, int out_size, void* d_ws, size_t ws_size,
                              hipStream_t stream) {
  const float* positions = (const float*)d_in[0];
  const float* kde       = (const float*)d_in[1];
  const float* weight    = (const float*)d_in[2];
  const float* offs      = (const float*)d_in[3];
  const int*   atom_idxs = (const int*)d_in[4];
  const int*   gsizes    = (const int*)d_in[5];
  float* out = (float*)d_out;

  unsigned* gmin_u = (unsigned*)d_ws;                 // NG*NB u32 = 512 KiB
  int* wl = (int*)d_ws + (size_t)NG * NB;             // WL_CAP+1 ints (~8 KiB)

  (void)hipMemsetAsync(gmin_u, 0xFF, (size_t)NG * NB * sizeof(unsigned), stream);

  build_worklist<<<dim3(1), dim3(256), 0, stream>>>(gsizes, wl);
  stage1_kernel<<<dim3(NG * NL * 2), dim3(256), 0, stream>>>(
      positions, kde, weight, offs, atom_idxs, wl, gmin_u);
  stage2_kernel<<<dim3(NB), dim3(256), 0, stream>>>(gmin_u, out);
}

// Round 6
// 41.891 us; speedup vs baseline: 4.2528x; 1.0703x over previous
//
#include <hip/hip_runtime.h>

#define NB 512
#define NATOMS 1024
#define NG 256
#define NL 8
#define NK 128

#define KBT 0.59616123f            // 0.0019872041 * 300
#define ALPHA_C 10.0f
#define LN2 0.6931471805599453f
#define LOG2E 1.4426950408889634f
#define INV2BW2 22.222221f         // 1/(2*0.15^2)
#define SCALE2 (INV2BW2 * LOG2E)   // log2-domain scale
#define LOG_NORM (-1.0170649f)     // log(128) + 3*log(2*pi*BW^2)

#define WL_CAP 2048                // max active (g,l) pairs = NG*NL
#define FILL_BLOCKS 128            // 128*256*16B = 512 KiB = NG*NB*4B exactly

__device__ __forceinline__ float fexp2(float x) { return __builtin_amdgcn_exp2f(x); }
__device__ __forceinline__ float flog2(float x) { return __builtin_amdgcn_logf(x); }

// monotone float<->uint key (unsigned order == float order), for atomicMin
__device__ __forceinline__ unsigned fkey(float f) {
  unsigned u = __float_as_uint(f);
  return (u & 0x80000000u) ? ~u : (u | 0x80000000u);
}
__device__ __forceinline__ float funkey(unsigned k) {
  unsigned u = (k & 0x80000000u) ? (k ^ 0x80000000u) : ~k;
  return __uint_as_float(u);
}

__device__ __forceinline__ float wred_min(float v) {
#pragma unroll
  for (int m = 32; m >= 1; m >>= 1) v = fminf(v, __shfl_xor(v, m, 64));
  return v;
}
__device__ __forceinline__ float wred_sum(float v) {
#pragma unroll
  for (int m = 32; m >= 1; m >>= 1) v += __shfl_xor(v, m, 64);
  return v;
}

// Grid = 1 + FILL_BLOCKS.  Block 0: prefix-sum nl over the 256 groups ->
// packed worklist of active (g,l) pairs (wl[WL_CAP] = count).  Blocks
// 1..FILL_BLOCKS: fill gmin_u with 0xFFFFFFFF, one uint4 per thread
// (128 blk * 256 thr * 16 B = 512 KiB -- the FULL buffer; round-5 bug was
// covering only 1/4 of it).
__global__ __launch_bounds__(256) void build_worklist(
    const int* __restrict__ gsizes, int* __restrict__ wl,
    uint4* __restrict__ gmin_u4) {
  const int t = threadIdx.x;
  if (blockIdx.x != 0) {
    const unsigned F = 0xFFFFFFFFu;
    gmin_u4[(blockIdx.x - 1) * 256 + t] = make_uint4(F, F, F, F);
    return;
  }
  const int lane = t & 63, wid = t >> 6;
  int gs = gsizes[t];
  int nl = gs < 1 ? 1 : (gs > NL ? NL : gs);
  int x = nl;                       // inclusive scan within wave
#pragma unroll
  for (int m = 1; m < 64; m <<= 1) {
    int y = __shfl_up(x, m, 64);
    if (lane >= m) x += y;
  }
  __shared__ int wsum[4];
  if (lane == 63) wsum[wid] = x;
  __syncthreads();
  int off = 0;
  for (int i = 0; i < wid; ++i) off += wsum[i];
  int inc = off + x, exc = inc - nl;
  for (int j = 0; j < nl; ++j) wl[exc + j] = (t << 3) | j;
  if (t == 255) wl[WL_CAP] = inc;   // total active pairs
}

// Block = one (worklist entry, b-half).  Thread t owns b = bq*256 + t and does
// the K=128 logsumexp serially: 4 online chains, each merging groups of 4 k's
// (1.25 exps/k, short dependence chains).  All in log2 domain.
__global__ __launch_bounds__(256) void stage1_kernel(
    const float* __restrict__ positions, const float* __restrict__ kde,
    const float* __restrict__ weight, const float* __restrict__ offs,
    const int* __restrict__ atom_idxs, const int* __restrict__ wl,
    unsigned* __restrict__ gmin_u) {
  const int w = blockIdx.x >> 1;
  const int bq = blockIdx.x & 1;
  const int count = wl[WL_CAP];
  if (w >= count) return;                 // contiguous inactive tail
  const int e = wl[w];
  const int g = e >> 3, l = e & 7;
  const int gl = g * NL + l;

  __shared__ __align__(16) float tab[NK][8];   // [mu'0..5, h, pad] (log2 dom.)

  const int t = threadIdx.x;
  const float* kb = kde + (size_t)gl * NK * 6;
  if (t < NK) {
    const float* mp = kb + t * 6;
    float m0 = mp[0], m1 = mp[1], m2 = mp[2], m3 = mp[3], m4 = mp[4], m5 = mp[5];
    float mu2 = m0 * m0 + m1 * m1 + m2 * m2 + m3 * m3 + m4 * m4 + m5 * m5;
    const float cf = 2.0f * SCALE2;
    float4 lo = make_float4(m0 * cf, m1 * cf, m2 * cf, m3 * cf);
    float4 hi = make_float4(m4 * cf, m5 * cf, -mu2 * SCALE2, 0.0f);
    *reinterpret_cast<float4*>(&tab[t][0]) = lo;
    *reinterpret_cast<float4*>(&tab[t][4]) = hi;
  }
  __syncthreads();

  const int b = bq * 256 + t;
  const int4 idx = *reinterpret_cast<const int4*>(atom_idxs + (gl << 2));
  const int ids[4] = {idx.x, idx.y, idx.z, idx.w};
  const float* pb = positions + (size_t)b * NATOMS * 3;
  float ax[4], ay[4], az[4];
#pragma unroll
  for (int j = 0; j < 4; ++j) {
    const float* pp = pb + ids[j] * 3;
    ax[j] = pp[0]; ay[j] = pp[1]; az[j] = pp[2];
  }
  const int PI_[6] = {0, 0, 0, 1, 1, 2};
  const int PJ_[6] = {1, 2, 3, 2, 3, 3};
  float d[6]; float x2 = 0.0f;
#pragma unroll
  for (int q = 0; q < 6; ++q) {
    float dx = ax[PI_[q]] - ax[PJ_[q]];
    float dy = ay[PI_[q]] - ay[PJ_[q]];
    float dz = az[PI_[q]] - az[PJ_[q]];
    float dd = dx * dx + dy * dy + dz * dz + 1e-12f;
    d[q] = sqrtf(dd);
    x2 += d[q] * d[q];
  }
  const float c2 = -x2 * SCALE2;     // constant over k (log2 domain)

  // 4 independent online-LSE chains; each step merges a group of 4 k's.
  float m_[4] = {-1e30f, -1e30f, -1e30f, -1e30f};
  float s_[4] = {0.0f, 0.0f, 0.0f, 0.0f};
  for (int k0 = 0; k0 < NK; k0 += 16) {
#pragma unroll
    for (int j = 0; j < 4; ++j) {
      const int kk = k0 + (j << 2);
      float v[4];
#pragma unroll
      for (int i = 0; i < 4; ++i) {
        const float4* r = reinterpret_cast<const float4*>(&tab[kk + i][0]);
        float4 A = r[0], Bv = r[1];
        float vv = Bv.z;
        vv = fmaf(A.x, d[0], vv);
        vv = fmaf(A.y, d[1], vv);
        vv = fmaf(A.z, d[2], vv);
        vv = fmaf(A.w, d[3], vv);
        vv = fmaf(Bv.x, d[4], vv);
        vv = fmaf(Bv.y, d[5], vv);
        v[i] = vv;
      }
      float gm = fmaxf(fmaxf(v[0], v[1]), fmaxf(v[2], v[3]));
      float p = fexp2(v[0] - gm) + fexp2(v[1] - gm)
              + fexp2(v[2] - gm) + fexp2(v[3] - gm);
      float nm = fmaxf(m_[j], gm);
      s_[j] = fmaf(s_[j], fexp2(m_[j] - nm), p * fexp2(gm - nm));
      m_[j] = nm;
    }
  }
  float M = fmaxf(fmaxf(m_[0], m_[1]), fmaxf(m_[2], m_[3]));
  float S = s_[0] * fexp2(m_[0] - M) + s_[1] * fexp2(m_[1] - M)
          + s_[2] * fexp2(m_[2] - M) + s_[3] * fexp2(m_[3] - M);

  float lse2 = c2 + M + flog2(S);            // log2(sum_k exp(v_k))
  float logP = lse2 * LN2 - LOG_NORM;
  float scaled = -KBT * logP * weight[gl] + offs[gl];
  atomicMin(&gmin_u[g * NB + b], fkey(scaled));
}

// One block per b: min over g, then logsumexp(-ALPHA*gmin) over g.
__global__ __launch_bounds__(256) void stage2_kernel(
    const unsigned* __restrict__ gmin_u, float* __restrict__ out) {
  const int b = blockIdx.x;
  const int t = threadIdx.x;
  const int lane = t & 63;
  const int wid = t >> 6;
  float v = funkey(gmin_u[t * NB + b]);
  __shared__ float sm[4], ss[4];
  float m = wred_min(v);
  if (lane == 0) sm[wid] = m;
  __syncthreads();
  float M = fminf(fminf(sm[0], sm[1]), fminf(sm[2], sm[3]));
  float e = fexp2(-ALPHA_C * LOG2E * (v - M));
  float s = wred_sum(e);
  if (lane == 0) ss[wid] = s;
  __syncthreads();
  if (t == 0) {
    float S = ss[0] + ss[1] + ss[2] + ss[3];
    out[b] = M - flog2(S) * LN2 / ALPHA_C;
  }
}

extern "C" void kernel_launch(void* const* d_in, const int* in_sizes, int n_in,
                              void* d_out, int out_size, void* d_ws, size_t ws_size,
                              hipStream_t stream) {
  const float* positions = (const float*)d_in[0];
  const float* kde       = (const float*)d_in[1];
  const float* weight    = (const float*)d_in[2];
  const float* offs      = (const float*)d_in[3];
  const int*   atom_idxs = (const int*)d_in[4];
  const int*   gsizes    = (const int*)d_in[5];
  float* out = (float*)d_out;

  unsigned* gmin_u = (unsigned*)d_ws;                 // NG*NB u32 = 512 KiB
  int* wl = (int*)d_ws + (size_t)NG * NB;             // WL_CAP+1 ints (~8 KiB)

  build_worklist<<<dim3(1 + FILL_BLOCKS), dim3(256), 0, stream>>>(
      gsizes, wl, (uint4*)gmin_u);
  stage1_kernel<<<dim3(NG * NL * 2), dim3(256), 0, stream>>>(
      positions, kde, weight, offs, atom_idxs, wl, gmin_u);
  stage2_kernel<<<dim3(NB), dim3(256), 0, stream>>>(gmin_u, out);
}